// Round 1
// baseline (590.258 us; speedup 1.0000x reference)
//
#include <hip/hip_runtime.h>
#include <math.h>

#define NPTS 65536
#define NV 6890
#define NVP 6912      // padded to multiple of 8 for clean unroll
#define NJ 24

// Kernel 0: precompute per-vertex (x, y, z, ||v||^2) in double into d_ws.
__global__ void prep_verts_k(const float* __restrict__ verts, double* __restrict__ vd) {
    int j = blockIdx.x * blockDim.x + threadIdx.x;
    if (j >= NVP) return;
    if (j < NV) {
        double x = (double)verts[3 * j + 0];
        double y = (double)verts[3 * j + 1];
        double z = (double)verts[3 * j + 2];
        vd[4 * j + 0] = x;
        vd[4 * j + 1] = y;
        vd[4 * j + 2] = z;
        vd[4 * j + 3] = x * x + y * y + z * z;
    } else {
        // sentinel rows: huge distance, never selected
        vd[4 * j + 0] = 0.0;
        vd[4 * j + 1] = 0.0;
        vd[4 * j + 2] = 0.0;
        vd[4 * j + 3] = 1e300;
    }
}

template <bool USE_PREP>
__launch_bounds__(256)
__global__ void smplnn_main(const float* __restrict__ xyz,
                            const float* __restrict__ rot,
                            const double* __restrict__ vd,
                            const float* __restrict__ verts_f,
                            const float* __restrict__ sw,
                            const float* __restrict__ bt,
                            float* __restrict__ out) {
    __shared__ float bts[NJ * 16];
    int i = blockIdx.x * blockDim.x + threadIdx.x;
    for (int t = threadIdx.x; t < NJ * 16; t += blockDim.x) bts[t] = bt[t];
    __syncthreads();

    float xf = xyz[3 * i + 0];
    float yf = xyz[3 * i + 1];
    float zf = xyz[3 * i + 2];

    // argmin_j ( ||v_j||^2 - 2 x . v_j )   in double for exact argmin
    double nx = -2.0 * (double)xf;
    double ny = -2.0 * (double)yf;
    double nz = -2.0 * (double)zf;

    double best = 1e301;
    int bi = 0;
    if (USE_PREP) {
        #pragma unroll 8
        for (int j = 0; j < NVP; ++j) {
            double vx = vd[4 * j + 0];
            double vy = vd[4 * j + 1];
            double vz = vd[4 * j + 2];
            double vn = vd[4 * j + 3];
            double s = fma(vx, nx, fma(vy, ny, fma(vz, nz, vn)));
            if (s < best) { best = s; bi = j; }
        }
    } else {
        #pragma unroll 4
        for (int j = 0; j < NV; ++j) {
            double vx = (double)verts_f[3 * j + 0];
            double vy = (double)verts_f[3 * j + 1];
            double vz = (double)verts_f[3 * j + 2];
            double vn = fma(vx, vx, fma(vy, vy, vz * vz));
            double s = fma(vx, nx, fma(vy, ny, fma(vz, nz, vn)));
            if (s < best) { best = s; bi = j; }
        }
    }

    // T_fwd = W[bi] @ bone_transforms(24x16)
    const float* W = &sw[bi * NJ];
    float T[16];
    #pragma unroll
    for (int r = 0; r < 16; ++r) T[r] = 0.0f;
    #pragma unroll
    for (int k = 0; k < NJ; ++k) {
        float w = W[k];
        #pragma unroll
        for (int r = 0; r < 16; ++r) T[r] = fmaf(w, bts[16 * k + r], T[r]);
    }

    // x_bar = T[:3,:3] @ x + T[:3,3]
    float xb0 = T[0] * xf + T[1] * yf + T[2]  * zf + T[3];
    float xb1 = T[4] * xf + T[5] * yf + T[6]  * zf + T[7];
    float xb2 = T[8] * xf + T[9] * yf + T[10] * zf + T[11];

    // rotation_hat from quaternion (r,x,y,z), normalized
    float qr = rot[4 * i + 0];
    float qx = rot[4 * i + 1];
    float qy = rot[4 * i + 2];
    float qz = rot[4 * i + 3];
    float inv = 1.0f / sqrtf(qr * qr + qx * qx + qy * qy + qz * qz);
    qr *= inv; qx *= inv; qy *= inv; qz *= inv;

    float Rh[9];
    Rh[0] = 1.0f - 2.0f * (qy * qy + qz * qz);
    Rh[1] = 2.0f * (qx * qy - qr * qz);
    Rh[2] = 2.0f * (qx * qz + qr * qy);
    Rh[3] = 2.0f * (qx * qy + qr * qz);
    Rh[4] = 1.0f - 2.0f * (qx * qx + qz * qz);
    Rh[5] = 2.0f * (qy * qz - qr * qx);
    Rh[6] = 2.0f * (qx * qz - qr * qy);
    Rh[7] = 2.0f * (qy * qz + qr * qx);
    Rh[8] = 1.0f - 2.0f * (qx * qx + qy * qy);

    // rotation_bar = T[:3,:3] @ Rh
    float RB[9];
    #pragma unroll
    for (int r = 0; r < 3; ++r) {
        #pragma unroll
        for (int c = 0; c < 3; ++c) {
            RB[3 * r + c] = T[4 * r + 0] * Rh[c]
                          + T[4 * r + 1] * Rh[3 + c]
                          + T[4 * r + 2] * Rh[6 + c];
        }
    }

    // outputs: x_bar [NPTS*3] | rotation_bar [NPTS*9] | T_fwd [NPTS*16]
    out[3 * i + 0] = xb0;
    out[3 * i + 1] = xb1;
    out[3 * i + 2] = xb2;
    float* ob = out + 3 * NPTS + 9 * i;
    #pragma unroll
    for (int k = 0; k < 9; ++k) ob[k] = RB[k];
    float* ot = out + 12 * NPTS + 16 * i;
    #pragma unroll
    for (int k = 0; k < 16; ++k) ot[k] = T[k];
}

extern "C" void kernel_launch(void* const* d_in, const int* in_sizes, int n_in,
                              void* d_out, int out_size, void* d_ws, size_t ws_size,
                              hipStream_t stream) {
    const float* xyz   = (const float*)d_in[0];
    const float* rot   = (const float*)d_in[1];
    const float* verts = (const float*)d_in[2];
    const float* sw    = (const float*)d_in[3];
    const float* bt    = (const float*)d_in[4];
    float* out = (float*)d_out;

    const size_t need = (size_t)NVP * 4 * sizeof(double);
    if (ws_size >= need && d_ws != nullptr) {
        double* vd = (double*)d_ws;
        prep_verts_k<<<(NVP + 255) / 256, 256, 0, stream>>>(verts, vd);
        smplnn_main<true><<<NPTS / 256, 256, 0, stream>>>(xyz, rot, vd, verts, sw, bt, out);
    } else {
        smplnn_main<false><<<NPTS / 256, 256, 0, stream>>>(xyz, rot, nullptr, verts, sw, bt, out);
    }
}

// Round 2
// 397.753 us; speedup vs baseline: 1.4840x; 1.4840x over previous
//
#include <hip/hip_runtime.h>
#include <math.h>

#define NPTS 65536
#define NV 6890
#define NVP 6912            // padded: 8 slices x 864
#define NSLICE 8
#define SLICE_LEN 864       // NVP / NSLICE
#define PTS_PER_BLK 64
#define NJ 24

// Kernel 0: precompute per-vertex (x, y, z, ||v||^2) in double into d_ws.
__global__ void prep_verts_k(const float* __restrict__ verts, double* __restrict__ vd) {
    int j = blockIdx.x * blockDim.x + threadIdx.x;
    if (j >= NVP) return;
    if (j < NV) {
        double x = (double)verts[3 * j + 0];
        double y = (double)verts[3 * j + 1];
        double z = (double)verts[3 * j + 2];
        vd[4 * j + 0] = x;
        vd[4 * j + 1] = y;
        vd[4 * j + 2] = z;
        vd[4 * j + 3] = x * x + y * y + z * z;
    } else {
        vd[4 * j + 0] = 0.0;
        vd[4 * j + 1] = 0.0;
        vd[4 * j + 2] = 0.0;
        vd[4 * j + 3] = 1e300;  // sentinel: never selected
    }
}

__launch_bounds__(512)
__global__ void smplnn_main(const float* __restrict__ xyz,
                            const float* __restrict__ rot,
                            const double* __restrict__ vd,
                            const float* __restrict__ sw,
                            const float* __restrict__ bt,
                            float* __restrict__ out) {
    __shared__ float bts[NJ * 16];
    __shared__ double sbest[512];
    __shared__ int sidx[512];

    const int tid = threadIdx.x;
    const int pl = tid & 63;          // point-in-block (lane)
    const int slice = tid >> 6;       // wave id = vertex slice
    const int i = blockIdx.x * PTS_PER_BLK + pl;

    for (int t = tid; t < NJ * 16; t += 512) bts[t] = bt[t];

    const float xf = xyz[3 * i + 0];
    const float yf = xyz[3 * i + 1];
    const float zf = xyz[3 * i + 2];

    const double nx = -2.0 * (double)xf;
    const double ny = -2.0 * (double)yf;
    const double nz = -2.0 * (double)zf;

    // scan my slice:  s = ||v||^2 - 2 x.v   (exact f64 argmin)
    double best = 1e301;
    int bi = 0;
    const double* __restrict__ vp = vd + (size_t)slice * SLICE_LEN * 4;
    const int jbase = slice * SLICE_LEN;
    #pragma unroll 8
    for (int j = 0; j < SLICE_LEN; ++j) {
        double vx = vp[4 * j + 0];
        double vy = vp[4 * j + 1];
        double vz = vp[4 * j + 2];
        double vn = vp[4 * j + 3];
        double s = fma(vx, nx, fma(vy, ny, fma(vz, nz, vn)));
        if (s < best) { best = s; bi = jbase + j; }
    }

    sbest[tid] = best;
    sidx[tid] = bi;
    __syncthreads();

    if (slice != 0) return;

    // merge 8 slices (ascending slice order + strict < keeps lowest index)
    #pragma unroll
    for (int s2 = 1; s2 < NSLICE; ++s2) {
        double b = sbest[pl + 64 * s2];
        int ix = sidx[pl + 64 * s2];
        if (b < best) { best = b; bi = ix; }
    }

    // T_fwd = W[bi] @ bone_transforms(24x16)
    const float* W = &sw[bi * NJ];
    float T[16];
    #pragma unroll
    for (int r = 0; r < 16; ++r) T[r] = 0.0f;
    #pragma unroll
    for (int k = 0; k < NJ; ++k) {
        float w = W[k];
        #pragma unroll
        for (int r = 0; r < 16; ++r) T[r] = fmaf(w, bts[16 * k + r], T[r]);
    }

    // x_bar = T[:3,:3] @ x + T[:3,3]
    float xb0 = T[0] * xf + T[1] * yf + T[2]  * zf + T[3];
    float xb1 = T[4] * xf + T[5] * yf + T[6]  * zf + T[7];
    float xb2 = T[8] * xf + T[9] * yf + T[10] * zf + T[11];

    // rotation_hat from quaternion (r,x,y,z), normalized
    float qr = rot[4 * i + 0];
    float qx = rot[4 * i + 1];
    float qy = rot[4 * i + 2];
    float qz = rot[4 * i + 3];
    float inv = 1.0f / sqrtf(qr * qr + qx * qx + qy * qy + qz * qz);
    qr *= inv; qx *= inv; qy *= inv; qz *= inv;

    float Rh[9];
    Rh[0] = 1.0f - 2.0f * (qy * qy + qz * qz);
    Rh[1] = 2.0f * (qx * qy - qr * qz);
    Rh[2] = 2.0f * (qx * qz + qr * qy);
    Rh[3] = 2.0f * (qx * qy + qr * qz);
    Rh[4] = 1.0f - 2.0f * (qx * qx + qz * qz);
    Rh[5] = 2.0f * (qy * qz - qr * qx);
    Rh[6] = 2.0f * (qx * qz - qr * qy);
    Rh[7] = 2.0f * (qy * qz + qr * qx);
    Rh[8] = 1.0f - 2.0f * (qx * qx + qy * qy);

    // rotation_bar = T[:3,:3] @ Rh
    float RB[9];
    #pragma unroll
    for (int r = 0; r < 3; ++r) {
        #pragma unroll
        for (int c = 0; c < 3; ++c) {
            RB[3 * r + c] = T[4 * r + 0] * Rh[c]
                          + T[4 * r + 1] * Rh[3 + c]
                          + T[4 * r + 2] * Rh[6 + c];
        }
    }

    // outputs: x_bar [NPTS*3] | rotation_bar [NPTS*9] | T_fwd [NPTS*16]
    out[3 * i + 0] = xb0;
    out[3 * i + 1] = xb1;
    out[3 * i + 2] = xb2;
    float* ob = out + 3 * NPTS + 9 * i;
    #pragma unroll
    for (int k = 0; k < 9; ++k) ob[k] = RB[k];
    float* ot = out + 12 * NPTS + 16 * i;
    #pragma unroll
    for (int k = 0; k < 16; ++k) ot[k] = T[k];
}

extern "C" void kernel_launch(void* const* d_in, const int* in_sizes, int n_in,
                              void* d_out, int out_size, void* d_ws, size_t ws_size,
                              hipStream_t stream) {
    const float* xyz   = (const float*)d_in[0];
    const float* rot   = (const float*)d_in[1];
    const float* verts = (const float*)d_in[2];
    const float* sw    = (const float*)d_in[3];
    const float* bt    = (const float*)d_in[4];
    float* out = (float*)d_out;

    double* vd = (double*)d_ws;
    prep_verts_k<<<(NVP + 255) / 256, 256, 0, stream>>>(verts, vd);
    smplnn_main<<<NPTS / PTS_PER_BLK, 512, 0, stream>>>(xyz, rot, vd, sw, bt, out);
}

// Round 3
// 184.347 us; speedup vs baseline: 3.2019x; 2.1576x over previous
//
#include <hip/hip_runtime.h>
#include <math.h>

#define NPTS 65536
#define NV 6890
#define NVP 6912            // padded: 8 slices x 864
#define NSLICE 8
#define SLICE_LEN 864       // NVP / NSLICE
#define PTS_PER_BLK 64
#define NJ 24

// Kernel 0: precompute per-vertex (x, y, z, ||v||^2) in double into d_ws.
__global__ void prep_verts_k(const float* __restrict__ verts, double* __restrict__ vd) {
    int j = blockIdx.x * blockDim.x + threadIdx.x;
    if (j >= NVP) return;
    if (j < NV) {
        double x = (double)verts[3 * j + 0];
        double y = (double)verts[3 * j + 1];
        double z = (double)verts[3 * j + 2];
        vd[4 * j + 0] = x;
        vd[4 * j + 1] = y;
        vd[4 * j + 2] = z;
        vd[4 * j + 3] = x * x + y * y + z * z;
    } else {
        vd[4 * j + 0] = 0.0;
        vd[4 * j + 1] = 0.0;
        vd[4 * j + 2] = 0.0;
        vd[4 * j + 3] = 1e300;  // sentinel: never selected
    }
}

__launch_bounds__(512)
__global__ void smplnn_main(const float* __restrict__ xyz,
                            const float* __restrict__ rot,
                            const double* __restrict__ vd,
                            const float* __restrict__ sw,
                            const float* __restrict__ bt,
                            float* __restrict__ out) {
    __shared__ float bts[NJ * 16];
    __shared__ double sbest[512];
    __shared__ int sidx[512];

    const int tid = threadIdx.x;
    const int pl = tid & 63;          // point-in-block (lane)
    // Wave-uniform slice index, made PROVABLY uniform so the compiler can
    // stream vertices through the scalar (SMEM) pipe into SGPRs.
    const int slice = __builtin_amdgcn_readfirstlane(tid >> 6);
    const int i = blockIdx.x * PTS_PER_BLK + pl;

    for (int t = tid; t < NJ * 16; t += 512) bts[t] = bt[t];

    const float xf = xyz[3 * i + 0];
    const float yf = xyz[3 * i + 1];
    const float zf = xyz[3 * i + 2];

    const double nx = -2.0 * (double)xf;
    const double ny = -2.0 * (double)yf;
    const double nz = -2.0 * (double)zf;

    // scan my slice:  s = ||v||^2 - 2 x.v   (exact f64 argmin)
    double best = 1e301;
    int bi = 0;
    const double2* __restrict__ vp =
        (const double2*)(vd + (size_t)slice * SLICE_LEN * 4);
    #pragma unroll 8
    for (int j = 0; j < SLICE_LEN; ++j) {
        double2 va = vp[2 * j + 0];   // (x, y)  -- wave-uniform address
        double2 vb = vp[2 * j + 1];   // (z, n)
        double s = fma(va.x, nx, fma(va.y, ny, fma(vb.x, nz, vb.y)));
        if (s < best) { best = s; bi = j; }
    }
    bi += slice * SLICE_LEN;

    sbest[tid] = best;
    sidx[tid] = bi;
    __syncthreads();

    if (slice != 0) return;

    // merge 8 slices (ascending slice order + strict < keeps lowest index)
    #pragma unroll
    for (int s2 = 1; s2 < NSLICE; ++s2) {
        double b = sbest[pl + 64 * s2];
        int ix = sidx[pl + 64 * s2];
        if (b < best) { best = b; bi = ix; }
    }

    // T_fwd = W[bi] @ bone_transforms(24x16)
    const float* W = &sw[bi * NJ];
    float T[16];
    #pragma unroll
    for (int r = 0; r < 16; ++r) T[r] = 0.0f;
    #pragma unroll
    for (int k = 0; k < NJ; ++k) {
        float w = W[k];
        #pragma unroll
        for (int r = 0; r < 16; ++r) T[r] = fmaf(w, bts[16 * k + r], T[r]);
    }

    // x_bar = T[:3,:3] @ x + T[:3,3]
    float xb0 = T[0] * xf + T[1] * yf + T[2]  * zf + T[3];
    float xb1 = T[4] * xf + T[5] * yf + T[6]  * zf + T[7];
    float xb2 = T[8] * xf + T[9] * yf + T[10] * zf + T[11];

    // rotation_hat from quaternion (r,x,y,z), normalized
    float qr = rot[4 * i + 0];
    float qx = rot[4 * i + 1];
    float qy = rot[4 * i + 2];
    float qz = rot[4 * i + 3];
    float inv = 1.0f / sqrtf(qr * qr + qx * qx + qy * qy + qz * qz);
    qr *= inv; qx *= inv; qy *= inv; qz *= inv;

    float Rh[9];
    Rh[0] = 1.0f - 2.0f * (qy * qy + qz * qz);
    Rh[1] = 2.0f * (qx * qy - qr * qz);
    Rh[2] = 2.0f * (qx * qz + qr * qy);
    Rh[3] = 2.0f * (qx * qy + qr * qz);
    Rh[4] = 1.0f - 2.0f * (qx * qx + qz * qz);
    Rh[5] = 2.0f * (qy * qz - qr * qx);
    Rh[6] = 2.0f * (qx * qz - qr * qy);
    Rh[7] = 2.0f * (qy * qz + qr * qx);
    Rh[8] = 1.0f - 2.0f * (qx * qx + qy * qy);

    // rotation_bar = T[:3,:3] @ Rh
    float RB[9];
    #pragma unroll
    for (int r = 0; r < 3; ++r) {
        #pragma unroll
        for (int c = 0; c < 3; ++c) {
            RB[3 * r + c] = T[4 * r + 0] * Rh[c]
                          + T[4 * r + 1] * Rh[3 + c]
                          + T[4 * r + 2] * Rh[6 + c];
        }
    }

    // outputs: x_bar [NPTS*3] | rotation_bar [NPTS*9] | T_fwd [NPTS*16]
    out[3 * i + 0] = xb0;
    out[3 * i + 1] = xb1;
    out[3 * i + 2] = xb2;
    float* ob = out + 3 * NPTS + 9 * i;
    #pragma unroll
    for (int k = 0; k < 9; ++k) ob[k] = RB[k];
    float* ot = out + 12 * NPTS + 16 * i;
    #pragma unroll
    for (int k = 0; k < 16; ++k) ot[k] = T[k];
}

extern "C" void kernel_launch(void* const* d_in, const int* in_sizes, int n_in,
                              void* d_out, int out_size, void* d_ws, size_t ws_size,
                              hipStream_t stream) {
    const float* xyz   = (const float*)d_in[0];
    const float* rot   = (const float*)d_in[1];
    const float* verts = (const float*)d_in[2];
    const float* sw    = (const float*)d_in[3];
    const float* bt    = (const float*)d_in[4];
    float* out = (float*)d_out;

    double* vd = (double*)d_ws;
    prep_verts_k<<<(NVP + 255) / 256, 256, 0, stream>>>(verts, vd);
    smplnn_main<<<NPTS / PTS_PER_BLK, 512, 0, stream>>>(xyz, rot, vd, sw, bt, out);
}